// Round 24
// baseline (147.423 us; speedup 1.0000x reference)
//
#include <hip/hip_runtime.h>

#define H_ 96
#define W_ 96
#define NV (H_ * W_)      // 9216 = 16 waves * 576 = 9 * 1024
#define NT 1024
#define WELEM 576
#define NSUB 9

#define WS_STRIDE (64 * 1024)   // per image: Ka u32[9216] @0, Pa u16[9216] @36864

__device__ __forceinline__ float keyToFloat(unsigned int k) {
  return __uint_as_float((k & 0x80000000u) ? (k ^ 0x80000000u) : ~k);
}
__device__ __forceinline__ unsigned int bitsToKey(unsigned int b) {
  return b ^ ((b & 0x80000000u) ? 0xFFFFFFFFu : 0x80000000u);
}

// ======================= Kernel A: radix sort only =======================
// LDS: Ka 36864 + Kb 36864 + Pa 18432 + Pb 18432 + hist 16384 = 126976 B
__global__ __launch_bounds__(NT, 1)
void kSort(const float* __restrict__ x, unsigned char* __restrict__ ws) {
  __shared__ unsigned int arenaW[126976 / 4];
  __shared__ unsigned int waveS[16];
  __shared__ unsigned int waveB[16];
  unsigned char* arena = (unsigned char*)arenaW;
  unsigned int*   Ka   = (unsigned int*)(arena);
  unsigned int*   Kb   = (unsigned int*)(arena + 36864);
  unsigned short* Pa   = (unsigned short*)(arena + 73728);
  unsigned short* Pb   = (unsigned short*)(arena + 92160);
  unsigned int*   hist = (unsigned int*)(arena + 110592);

  const int tid = threadIdx.x;
  const int wv = tid >> 6, ln = tid & 63;
  const float* img = x + (size_t)blockIdx.x * NV;
  unsigned char* w = ws + (size_t)blockIdx.x * WS_STRIDE;

  const int wbase = wv * WELEM;
  for (int pass = 0; pass < 4; ++pass) {
    const unsigned int*   Ks = (pass & 1) ? Kb : Ka;
    const unsigned short* Ps = (pass & 1) ? Pb : Pa;
    unsigned int*   Kd = (pass & 1) ? Ka : Kb;
    unsigned short* Pd = (pass & 1) ? Pa : Pb;
    const int sh = pass << 3;

    for (int i = tid; i < 16 * 256; i += NT) hist[i] = 0u;
    __syncthreads();

    unsigned kreg[NSUB];
    unsigned rk[NSUB];
    #pragma unroll
    for (int j = 0; j < NSUB; ++j) {
      const int e = wbase + j * 64 + ln;
      const unsigned k = (pass == 0) ? bitsToKey(__float_as_uint(img[e])) : Ks[e];
      kreg[j] = k;
      const unsigned d = (k >> sh) & 255u;
      unsigned long long mask = ~0ull;
      #pragma unroll
      for (int b = 0; b < 8; ++b) {
        const unsigned long long bb = __ballot((d >> b) & 1u);
        mask &= ((d >> b) & 1u) ? bb : ~bb;
      }
      const unsigned long long below = mask & ((1ull << ln) - 1ull);
      const unsigned old = hist[wv * 256 + d];
      rk[j] = (d << 16) | (old + (unsigned)__popcll(below));
      if (below == 0ull)
        hist[wv * 256 + d] = old + (unsigned)__popcll(mask);
    }
    __syncthreads();

    {
      unsigned v0, v1, v2, v3;
      const int s0 = tid * 4;
      v0 = hist[((s0 + 0) & 15) * 256 + ((s0 + 0) >> 4)];
      v1 = hist[((s0 + 1) & 15) * 256 + ((s0 + 1) >> 4)];
      v2 = hist[((s0 + 2) & 15) * 256 + ((s0 + 2) >> 4)];
      v3 = hist[((s0 + 3) & 15) * 256 + ((s0 + 3) >> 4)];
      const unsigned ts = v0 + v1 + v2 + v3;
      unsigned incl = ts;
      #pragma unroll
      for (int off = 1; off < 64; off <<= 1) {
        const unsigned n = (unsigned)__shfl_up((int)incl, off, 64);
        if (ln >= off) incl += n;
      }
      if (ln == 63) waveS[wv] = incl;
      __syncthreads();
      if (tid < 16) {
        unsigned s = 0;
        for (int q = 0; q < 16; ++q) { if (q == tid) break; s += waveS[q]; }
        waveB[tid] = s;
      }
      __syncthreads();
      unsigned run = waveB[wv] + (incl - ts);
      hist[((s0 + 0) & 15) * 256 + ((s0 + 0) >> 4)] = run; run += v0;
      hist[((s0 + 1) & 15) * 256 + ((s0 + 1) >> 4)] = run; run += v1;
      hist[((s0 + 2) & 15) * 256 + ((s0 + 2) >> 4)] = run; run += v2;
      hist[((s0 + 3) & 15) * 256 + ((s0 + 3) >> 4)] = run;
    }
    __syncthreads();

    #pragma unroll
    for (int j = 0; j < NSUB; ++j) {
      const int e = wbase + j * 64 + ln;
      const unsigned d = rk[j] >> 16;
      const unsigned dest = hist[wv * 256 + d] + (rk[j] & 0xFFFFu);
      Kd[dest] = kreg[j];
      Pd[dest] = (pass == 0) ? (unsigned short)e : Ps[e];
    }
    __syncthreads();
  }

  // write out sorted Ka/Pa (coalesced)
  {
    unsigned int* dK = (unsigned int*)(w);
    for (int i = tid; i < NV; i += NT) dK[i] = Ka[i];
    unsigned int* dP = (unsigned int*)(w + 36864);
    const unsigned int* sP = (const unsigned int*)Pa;
    for (int i = tid; i < NV / 2; i += NT) dP[i] = sP[i];
  }
}

// ======================= Kernel B: UF + entropy =======================
// LDS: Ka 36864 + Pa 18432 + parU 18432 + claim 36864 + incB 9216 = 119808 B
__global__ __launch_bounds__(NT, 1)
void kUF(const float* __restrict__ x, const unsigned char* __restrict__ ws,
         float* __restrict__ out) {
  __shared__ unsigned int arenaW[119808 / 4];
  __shared__ double Td[16], Sd[16];
  unsigned char* arena = (unsigned char*)arenaW;
  unsigned int*   Ka    = (unsigned int*)(arena);
  unsigned short* Pa    = (unsigned short*)(arena + 36864);
  unsigned short* parU  = (unsigned short*)(arena + 55296);
  unsigned int*   claim = (unsigned int*)(arena + 73728);
  unsigned char*  incB  = (unsigned char*)(arena + 110592);

  const int tid = threadIdx.x;
  const int wv = tid >> 6, ln = tid & 63;
  const float* img = x + (size_t)blockIdx.x * NV;
  const unsigned char* w = ws + (size_t)blockIdx.x * WS_STRIDE;

  // load sorted arrays (coalesced)
  {
    const unsigned int* sK = (const unsigned int*)(w);
    for (int i = tid; i < NV; i += NT) Ka[i] = sK[i];
    const unsigned int* sP = (const unsigned int*)(w + 36864);
    unsigned int* dP = (unsigned int*)Pa;
    for (int i = tid; i < NV / 2; i += NT) dP[i] = sP[i];
  }
  __syncthreads();

  // P3: UF init + claim init + inclusion bits (coalesced img reads)
  for (int t = tid; t < NV; t += NT) parU[Pa[t]] = (unsigned short)(0x8000u | (unsigned)t);
  for (int i = tid; i < NV; i += NT) claim[i] = 0xFFFFFFFFu;
  for (int v = tid; v < NV; v += NT) {
    const unsigned kc = bitsToKey(__float_as_uint(img[v]));
    const int r = v / W_, c = v - r * W_;
    unsigned b = 0;
    if (c > 0       && bitsToKey(__float_as_uint(img[v - 1]))  <= kc) b |= 1u;
    if (c < W_ - 1  && bitsToKey(__float_as_uint(img[v + 1]))  <= kc) b |= 2u;
    if (r > 0       && bitsToKey(__float_as_uint(img[v - W_])) <= kc) b |= 4u;
    if (r < H_ - 1  && bitsToKey(__float_as_uint(img[v + W_])) <= kc) b |= 8u;
    incB[v] = (unsigned char)b;
  }
  __syncthreads();

  // P4: block-wide parallel-commit Kruskal, epoch claims
  double T = 0.0, S = 0.0;
  unsigned gr = 0;
  for (int ch = 0; ch < NV / NT; ++ch) {
    const int t = ch * NT + tid;
    const int vid = (int)Pa[t];
    const float vt = keyToFloat(Ka[t]);
    const int nv0 = vid - 1, nv1 = vid + 1, nv2 = vid - W_, nv3 = vid + W_;
    const unsigned ib = incB[vid];
    const bool inc0 = (ib & 1u) != 0u;
    const bool inc1 = (ib & 2u) != 0u;
    const bool inc2 = (ib & 4u) != 0u;
    const bool inc3 = (ib & 8u) != 0u;
    int x0 = inc0 ? nv0 : vid, x1 = inc1 ? nv1 : vid;
    int x2 = inc2 ? nv2 : vid, x3 = inc3 ? nv3 : vid;
    unsigned e0 = 0, e1 = 0, e2 = 0, e3 = 0;
    bool committed = false;

    for (;;) {
      const unsigned cval = ((0x000FFFFFu - gr) << 10) | (unsigned)tid;
      ++gr;
      if (!committed) {
        bool d0 = !inc0, d1 = !inc1, d2 = !inc2, d3 = !inc3;
        while (!(d0 && d1 && d2 && d3)) {
          if (!d0) { unsigned e = parU[x0]; if (e & 0x8000u) { e0 = e; d0 = true; } else x0 = (int)e; }
          if (!d1) { unsigned e = parU[x1]; if (e & 0x8000u) { e1 = e; d1 = true; } else x1 = (int)e; }
          if (!d2) { unsigned e = parU[x2]; if (e & 0x8000u) { e2 = e; d2 = true; } else x2 = (int)e; }
          if (!d3) { unsigned e = parU[x3]; if (e & 0x8000u) { e3 = e; d3 = true; } else x3 = (int)e; }
        }
        if (inc0 && nv0 != x0) parU[nv0] = (unsigned short)x0;
        if (inc1 && nv1 != x1) parU[nv1] = (unsigned short)x1;
        if (inc2 && nv2 != x2) parU[nv2] = (unsigned short)x2;
        if (inc3 && nv3 != x3) parU[nv3] = (unsigned short)x3;
      }
      bool u0 = false, u1 = false, u2 = false, u3 = false, uv = false;
      int mvid = vid;
      int rr0 = 0, rr1 = 0, rr2 = 0, rr3 = 0;
      if (!committed) {
        int mrank = t;
        rr0 = (int)(e0 & 0x3FFFu); rr1 = (int)(e1 & 0x3FFFu);
        rr2 = (int)(e2 & 0x3FFFu); rr3 = (int)(e3 & 0x3FFFu);
        if (inc0 && rr0 < mrank) { mrank = rr0; mvid = x0; }
        if (inc1 && rr1 < mrank) { mrank = rr1; mvid = x1; }
        if (inc2 && rr2 < mrank) { mrank = rr2; mvid = x2; }
        if (inc3 && rr3 < mrank) { mrank = rr3; mvid = x3; }
        u0 = inc0 && (x0 != mvid);
        u1 = inc1 && (x1 != mvid) && !(inc0 && x1 == x0);
        u2 = inc2 && (x2 != mvid) && !(inc0 && x2 == x0) && !(inc1 && x2 == x1);
        u3 = inc3 && (x3 != mvid) && !(inc0 && x3 == x0) && !(inc1 && x3 == x1) && !(inc2 && x3 == x2);
        uv = (mvid != vid);
        if (u0) atomicMin(&claim[x0], cval);
        if (u1) atomicMin(&claim[x1], cval);
        if (u2) atomicMin(&claim[x2], cval);
        if (u3) atomicMin(&claim[x3], cval);
        if (uv) atomicMin(&claim[vid], cval);
      }
      __syncthreads();
      if (!committed) {
        bool win = true;
        if (u0 && claim[x0] != cval) win = false;
        if (u1 && claim[x1] != cval) win = false;
        if (u2 && claim[x2] != cval) win = false;
        if (u3 && claim[x3] != cval) win = false;
        if (uv && claim[vid] != cval) win = false;
        if (win) {
          if (u0) { const float p = vt - keyToFloat(Ka[rr0]);
                    if (p > 0.0f) { T += (double)p; S += (double)(p * logf(p)); }
                    parU[x0] = (unsigned short)mvid; }
          if (u1) { const float p = vt - keyToFloat(Ka[rr1]);
                    if (p > 0.0f) { T += (double)p; S += (double)(p * logf(p)); }
                    parU[x1] = (unsigned short)mvid; }
          if (u2) { const float p = vt - keyToFloat(Ka[rr2]);
                    if (p > 0.0f) { T += (double)p; S += (double)(p * logf(p)); }
                    parU[x2] = (unsigned short)mvid; }
          if (u3) { const float p = vt - keyToFloat(Ka[rr3]);
                    if (p > 0.0f) { T += (double)p; S += (double)(p * logf(p)); }
                    parU[x3] = (unsigned short)mvid; }
          if (uv) parU[vid] = (unsigned short)mvid;
          committed = true;
        }
      }
      if (__syncthreads_count(!committed ? 1 : 0) == 0) break;
    }
  }

  #pragma unroll
  for (int off = 32; off > 0; off >>= 1) {
    T += __shfl_down(T, off, 64);
    S += __shfl_down(S, off, 64);
  }
  if (ln == 0) { Td[wv] = T; Sd[wv] = S; }
  __syncthreads();
  if (tid == 0) {
    double Tt = 0.0, St = 0.0;
    for (int q = 0; q < 16; ++q) { Tt += Td[q]; St += Sd[q]; }
    out[blockIdx.x] = (Tt > 0.0) ? (float)(log(Tt) - St / Tt) : 0.0f;
  }
}

// ======================= Monolithic fallback (R23) =======================
__global__ __launch_bounds__(NT, 1)
void topo_mono(const float* __restrict__ x, float* __restrict__ out) {
  __shared__ unsigned int arenaW[136192 / 4];
  __shared__ unsigned int waveS[16];
  __shared__ unsigned int waveB[16];
  __shared__ double Td[16], Sd[16];
  unsigned char* arena = (unsigned char*)arenaW;
  unsigned int*   Ka    = (unsigned int*)(arena);
  unsigned int*   Kb    = (unsigned int*)(arena + 36864);
  unsigned short* Pa    = (unsigned short*)(arena + 73728);
  unsigned short* Pb    = (unsigned short*)(arena + 92160);
  unsigned int*   hist  = (unsigned int*)(arena + 110592);
  unsigned char*  incB  = (unsigned char*)(arena + 126976);
  unsigned short* parU  = (unsigned short*)(arena + 92160);
  unsigned int*   claim = (unsigned int*)(arena + 36864);

  const int tid = threadIdx.x;
  const int wv = tid >> 6, ln = tid & 63;
  const float* img = x + (size_t)blockIdx.x * NV;

  const int wbase = wv * WELEM;
  for (int pass = 0; pass < 4; ++pass) {
    const unsigned int*   Ks = (pass & 1) ? Kb : Ka;
    const unsigned short* Ps = (pass & 1) ? Pb : Pa;
    unsigned int*   Kd = (pass & 1) ? Ka : Kb;
    unsigned short* Pd = (pass & 1) ? Pa : Pb;
    const int sh = pass << 3;
    for (int i = tid; i < 16 * 256; i += NT) hist[i] = 0u;
    __syncthreads();
    unsigned kreg[NSUB];
    unsigned rk[NSUB];
    #pragma unroll
    for (int j = 0; j < NSUB; ++j) {
      const int e = wbase + j * 64 + ln;
      const unsigned k = (pass == 0) ? bitsToKey(__float_as_uint(img[e])) : Ks[e];
      kreg[j] = k;
      const unsigned d = (k >> sh) & 255u;
      unsigned long long mask = ~0ull;
      #pragma unroll
      for (int b = 0; b < 8; ++b) {
        const unsigned long long bb = __ballot((d >> b) & 1u);
        mask &= ((d >> b) & 1u) ? bb : ~bb;
      }
      const unsigned long long below = mask & ((1ull << ln) - 1ull);
      const unsigned old = hist[wv * 256 + d];
      rk[j] = (d << 16) | (old + (unsigned)__popcll(below));
      if (below == 0ull)
        hist[wv * 256 + d] = old + (unsigned)__popcll(mask);
    }
    __syncthreads();
    {
      unsigned v0, v1, v2, v3;
      const int s0 = tid * 4;
      v0 = hist[((s0 + 0) & 15) * 256 + ((s0 + 0) >> 4)];
      v1 = hist[((s0 + 1) & 15) * 256 + ((s0 + 1) >> 4)];
      v2 = hist[((s0 + 2) & 15) * 256 + ((s0 + 2) >> 4)];
      v3 = hist[((s0 + 3) & 15) * 256 + ((s0 + 3) >> 4)];
      const unsigned ts = v0 + v1 + v2 + v3;
      unsigned incl = ts;
      #pragma unroll
      for (int off = 1; off < 64; off <<= 1) {
        const unsigned n = (unsigned)__shfl_up((int)incl, off, 64);
        if (ln >= off) incl += n;
      }
      if (ln == 63) waveS[wv] = incl;
      __syncthreads();
      if (tid < 16) {
        unsigned s = 0;
        for (int q = 0; q < 16; ++q) { if (q == tid) break; s += waveS[q]; }
        waveB[tid] = s;
      }
      __syncthreads();
      unsigned run = waveB[wv] + (incl - ts);
      hist[((s0 + 0) & 15) * 256 + ((s0 + 0) >> 4)] = run; run += v0;
      hist[((s0 + 1) & 15) * 256 + ((s0 + 1) >> 4)] = run; run += v1;
      hist[((s0 + 2) & 15) * 256 + ((s0 + 2) >> 4)] = run; run += v2;
      hist[((s0 + 3) & 15) * 256 + ((s0 + 3) >> 4)] = run;
    }
    __syncthreads();
    #pragma unroll
    for (int j = 0; j < NSUB; ++j) {
      const int e = wbase + j * 64 + ln;
      const unsigned d = rk[j] >> 16;
      const unsigned dest = hist[wv * 256 + d] + (rk[j] & 0xFFFFu);
      Kd[dest] = kreg[j];
      Pd[dest] = (pass == 0) ? (unsigned short)e : Ps[e];
    }
    __syncthreads();
  }
  for (int t = tid; t < NV; t += NT) parU[Pa[t]] = (unsigned short)(0x8000u | (unsigned)t);
  for (int i = tid; i < NV; i += NT) claim[i] = 0xFFFFFFFFu;
  for (int v = tid; v < NV; v += NT) {
    const unsigned kc = bitsToKey(__float_as_uint(img[v]));
    const int r = v / W_, c = v - r * W_;
    unsigned b = 0;
    if (c > 0       && bitsToKey(__float_as_uint(img[v - 1]))  <= kc) b |= 1u;
    if (c < W_ - 1  && bitsToKey(__float_as_uint(img[v + 1]))  <= kc) b |= 2u;
    if (r > 0       && bitsToKey(__float_as_uint(img[v - W_])) <= kc) b |= 4u;
    if (r < H_ - 1  && bitsToKey(__float_as_uint(img[v + W_])) <= kc) b |= 8u;
    incB[v] = (unsigned char)b;
  }
  __syncthreads();
  double T = 0.0, S = 0.0;
  unsigned gr = 0;
  for (int ch = 0; ch < NV / NT; ++ch) {
    const int t = ch * NT + tid;
    const int vid = (int)Pa[t];
    const float vt = keyToFloat(Ka[t]);
    const int nv0 = vid - 1, nv1 = vid + 1, nv2 = vid - W_, nv3 = vid + W_;
    const unsigned ib = incB[vid];
    const bool inc0 = (ib & 1u) != 0u;
    const bool inc1 = (ib & 2u) != 0u;
    const bool inc2 = (ib & 4u) != 0u;
    const bool inc3 = (ib & 8u) != 0u;
    int x0 = inc0 ? nv0 : vid, x1 = inc1 ? nv1 : vid;
    int x2 = inc2 ? nv2 : vid, x3 = inc3 ? nv3 : vid;
    unsigned e0 = 0, e1 = 0, e2 = 0, e3 = 0;
    bool committed = false;
    for (;;) {
      const unsigned cval = ((0x000FFFFFu - gr) << 10) | (unsigned)tid;
      ++gr;
      if (!committed) {
        bool d0 = !inc0, d1 = !inc1, d2 = !inc2, d3 = !inc3;
        while (!(d0 && d1 && d2 && d3)) {
          if (!d0) { unsigned e = parU[x0]; if (e & 0x8000u) { e0 = e; d0 = true; } else x0 = (int)e; }
          if (!d1) { unsigned e = parU[x1]; if (e & 0x8000u) { e1 = e; d1 = true; } else x1 = (int)e; }
          if (!d2) { unsigned e = parU[x2]; if (e & 0x8000u) { e2 = e; d2 = true; } else x2 = (int)e; }
          if (!d3) { unsigned e = parU[x3]; if (e & 0x8000u) { e3 = e; d3 = true; } else x3 = (int)e; }
        }
        if (inc0 && nv0 != x0) parU[nv0] = (unsigned short)x0;
        if (inc1 && nv1 != x1) parU[nv1] = (unsigned short)x1;
        if (inc2 && nv2 != x2) parU[nv2] = (unsigned short)x2;
        if (inc3 && nv3 != x3) parU[nv3] = (unsigned short)x3;
      }
      bool u0 = false, u1 = false, u2 = false, u3 = false, uv = false;
      int mvid = vid;
      int rr0 = 0, rr1 = 0, rr2 = 0, rr3 = 0;
      if (!committed) {
        int mrank = t;
        rr0 = (int)(e0 & 0x3FFFu); rr1 = (int)(e1 & 0x3FFFu);
        rr2 = (int)(e2 & 0x3FFFu); rr3 = (int)(e3 & 0x3FFFu);
        if (inc0 && rr0 < mrank) { mrank = rr0; mvid = x0; }
        if (inc1 && rr1 < mrank) { mrank = rr1; mvid = x1; }
        if (inc2 && rr2 < mrank) { mrank = rr2; mvid = x2; }
        if (inc3 && rr3 < mrank) { mrank = rr3; mvid = x3; }
        u0 = inc0 && (x0 != mvid);
        u1 = inc1 && (x1 != mvid) && !(inc0 && x1 == x0);
        u2 = inc2 && (x2 != mvid) && !(inc0 && x2 == x0) && !(inc1 && x2 == x1);
        u3 = inc3 && (x3 != mvid) && !(inc0 && x3 == x0) && !(inc1 && x3 == x1) && !(inc2 && x3 == x2);
        uv = (mvid != vid);
        if (u0) atomicMin(&claim[x0], cval);
        if (u1) atomicMin(&claim[x1], cval);
        if (u2) atomicMin(&claim[x2], cval);
        if (u3) atomicMin(&claim[x3], cval);
        if (uv) atomicMin(&claim[vid], cval);
      }
      __syncthreads();
      if (!committed) {
        bool win = true;
        if (u0 && claim[x0] != cval) win = false;
        if (u1 && claim[x1] != cval) win = false;
        if (u2 && claim[x2] != cval) win = false;
        if (u3 && claim[x3] != cval) win = false;
        if (uv && claim[vid] != cval) win = false;
        if (win) {
          if (u0) { const float p = vt - keyToFloat(Ka[rr0]);
                    if (p > 0.0f) { T += (double)p; S += (double)(p * logf(p)); }
                    parU[x0] = (unsigned short)mvid; }
          if (u1) { const float p = vt - keyToFloat(Ka[rr1]);
                    if (p > 0.0f) { T += (double)p; S += (double)(p * logf(p)); }
                    parU[x1] = (unsigned short)mvid; }
          if (u2) { const float p = vt - keyToFloat(Ka[rr2]);
                    if (p > 0.0f) { T += (double)p; S += (double)(p * logf(p)); }
                    parU[x2] = (unsigned short)mvid; }
          if (u3) { const float p = vt - keyToFloat(Ka[rr3]);
                    if (p > 0.0f) { T += (double)p; S += (double)(p * logf(p)); }
                    parU[x3] = (unsigned short)mvid; }
          if (uv) parU[vid] = (unsigned short)mvid;
          committed = true;
        }
      }
      if (__syncthreads_count(!committed ? 1 : 0) == 0) break;
    }
  }
  #pragma unroll
  for (int off = 32; off > 0; off >>= 1) {
    T += __shfl_down(T, off, 64);
    S += __shfl_down(S, off, 64);
  }
  if (ln == 0) { Td[wv] = T; Sd[wv] = S; }
  __syncthreads();
  if (tid == 0) {
    double Tt = 0.0, St = 0.0;
    for (int q = 0; q < 16; ++q) { Tt += Td[q]; St += Sd[q]; }
    out[blockIdx.x] = (Tt > 0.0) ? (float)(log(Tt) - St / Tt) : 0.0f;
  }
}

extern "C" void kernel_launch(void* const* d_in, const int* in_sizes, int n_in,
                              void* d_out, int out_size, void* d_ws, size_t ws_size,
                              hipStream_t stream) {
  (void)n_in; (void)out_size;
  const float* x = (const float*)d_in[0];
  float* out = (float*)d_out;
  int n_img = in_sizes[0] / NV;   // 64
  if (n_img <= 0) n_img = 1;
  if (ws_size >= (size_t)n_img * WS_STRIDE) {
    unsigned char* ws = (unsigned char*)d_ws;
    kSort<<<n_img, NT, 0, stream>>>(x, ws);
    kUF<<<n_img, NT, 0, stream>>>(x, ws, out);
  } else {
    topo_mono<<<n_img, NT, 0, stream>>>(x, out);
  }
}